// Round 10
// baseline (576.162 us; speedup 1.0000x reference)
//
#include <hip/hip_runtime.h>
#include <hip/hip_bf16.h>
#include <math.h>
#include <stdint.h>

#define BATCH 64
#define SEQ   101
#define HID   512
#define NKQ   100      // N*K
#define KCLS  10
#define INV_TEMP 0.04419417382415922f   // 1/sqrt(512)

typedef short bf16x8 __attribute__((ext_vector_type(8)));
typedef float f32x4  __attribute__((ext_vector_type(4)));
typedef uint32_t u32x4 __attribute__((ext_vector_type(4)));

__device__ inline f32x4 vspl(float x) { return (f32x4){x, x, x, x}; }

// packed f32->bf16 RNE via compiler intrinsic (v_cvt_pk_bf16_f32).
__device__ inline uint32_t cvt2(float a, float b) {
    __hip_bfloat162 t = __float22bfloat162_rn(float2{a, b});
    uint32_t r;
    __builtin_memcpy(&r, &t, 4);
    return r;
}
// truncation split: x == hi + lo to ~2^-17 rel (q plane)
__device__ inline void split_bf16(float x, short& hi, short& lo) {
    uint32_t u = __builtin_bit_cast(uint32_t, x);
    hi = (short)(u >> 16);
    float hf = __builtin_bit_cast(float, u & 0xFFFF0000u);
    float l  = x - hf;
    lo = (short)(__builtin_bit_cast(uint32_t, l) >> 16);
}

// ---------------------------------------------------------------------------
// MLP-shaped fused kernel. Diagnosis (r7/r9 counters): kernel moves ~45 MB of
// POISON-COLD memory at ~1 TB/s effective -- latency-limited BW from shallow
// load bursts. This version keeps ~10 loads/wave in flight end-to-end:
//   * V-window-0 loads issued at KERNEL TOP (fly under q-stage + phase 1)
//   * V-window-1 + vN issued after phase 1 (fly under softmax)
//   * phase 3: double-windowed V prefetch (static idx), float2/b64 P reads
//   * phase 1: validated ring-4 fp32-k form (8 loads in flight)
// Phase 3 stays fp32-exact streaming PV with class-segmented U.
// LDS: q hi/lo 32.5 KB + sc 8.4 KB. grid 448: b=id&63 (XCD affinity),
// i-tile=id>>6. 512 thr = 8 waves. No workspace use.
// ---------------------------------------------------------------------------
#define QST 520    // qhi/qlo row stride (shorts): 512 + 8 pad

#define OFF_QLO 16640          // 16*520*2
#define POOLSZ  33280          // 2*16640

__global__ __launch_bounds__(512, 2)
void fused_attn(const float* __restrict__ q, const float* __restrict__ k,
                const float* __restrict__ v, const float* __restrict__ aw,
                float* __restrict__ out, float* __restrict__ attn) {
    __shared__ __align__(16) char pool[POOLSZ];
    __shared__ __align__(16) float sc[16][132];
    short (*qhi)[QST] = (short(*)[QST])(pool);
    short (*qlo)[QST] = (short(*)[QST])(pool + OFF_QLO);

    const int b   = blockIdx.x & 63;
    const int i0  = (blockIdx.x >> 6) * 16;
    const int tid = threadIdx.x;
    const int wv  = tid >> 6, lane = tid & 63;
    const int m   = lane & 15;
    const int g   = lane >> 4;
    const int kq  = g * 8;
    const int rq  = g * 4;
    const int j0w = wv * 16;

    const float* qb = q + (size_t)b * SEQ * HID;
    const float* kb = k + (size_t)b * SEQ * HID;
    const float* vb = v + (size_t)b * SEQ * HID;

    // phase-3 mapping, known at kernel top
    const int hp = tid & 127;          // float4 column index
    const int rg = tid >> 7;           // row group: rows rg*4..rg*4+3
    const int h4 = hp << 2;
    const float* vcol = vb + h4;

    // ---- EARLY ISSUE: V window 0 (j=0..4) -- flies under q-stage+phase1 ----
    f32x4 vbuf0[5], vbuf1[5];
    #pragma unroll
    for (int t = 0; t < 5; ++t)
        vbuf0[t] = *(const f32x4*)(vcol + (size_t)t * HID);

    // ---------------- stage q hi/lo (once) ---------------------------------
    #pragma unroll
    for (int s = 0; s < 4; ++s) {
        const int f = tid + s * 512;
        const int r = f >> 7, c = (f & 127) << 2;
        const int gi = i0 + r;
        f32x4 x = {};
        if (gi < SEQ) x = *(const f32x4*)(qb + (size_t)gi * HID + c);
        short4 hv, lv;
        split_bf16(x[0], hv.x, lv.x);
        split_bf16(x[1], hv.y, lv.y);
        split_bf16(x[2], hv.z, lv.z);
        split_bf16(x[3], hv.w, lv.w);
        *(short4*)&qhi[r][c] = hv;
        *(short4*)&qlo[r][c] = lv;
    }
    __syncthreads();

    // ---------------- phase 1: QK^T, k direct from global, ring-4 ----------
    f32x4 acc = {};
    {
        const int jg = j0w + m;
        const int jr = (jg > NKQ) ? NKQ : jg;   // clamp; junk rows finite
        const float* kr = kb + (size_t)jr * HID + kq;
        f32x4 kp0[4], kp1[4];
        #pragma unroll
        for (int d = 0; d < 4; ++d) {
            kp0[d] = *(const f32x4*)(kr + d * 32);
            kp1[d] = *(const f32x4*)(kr + d * 32 + 4);
        }
        #pragma unroll
        for (int ks = 0; ks < 16; ++ks) {
            const int cur = ks & 3;             // static after unroll
            u32x4 kw;
            kw[0] = cvt2(kp0[cur][0], kp0[cur][1]);
            kw[1] = cvt2(kp0[cur][2], kp0[cur][3]);
            kw[2] = cvt2(kp1[cur][0], kp1[cur][1]);
            kw[3] = cvt2(kp1[cur][2], kp1[cur][3]);
            if (ks + 4 < 16) {                  // refill ring slot
                kp0[cur] = *(const f32x4*)(kr + (ks + 4) * 32);
                kp1[cur] = *(const f32x4*)(kr + (ks + 4) * 32 + 4);
            }
            const bf16x8 kH = __builtin_bit_cast(bf16x8, kw);
            const bf16x8 qH = *(const bf16x8*)&qhi[m][ks * 32 + kq];
            const bf16x8 qL = *(const bf16x8*)&qlo[m][ks * 32 + kq];
            acc = __builtin_amdgcn_mfma_f32_16x16x32_bf16(qH, kH, acc, 0, 0, 0);
            acc = __builtin_amdgcn_mfma_f32_16x16x32_bf16(qL, kH, acc, 0, 0, 0);
        }
    }
    #pragma unroll
    for (int r = 0; r < 4; ++r)
        sc[rq + r][j0w + m] = acc[r];

    // ---- EARLY ISSUE: V window 1 (j=5..9) + vN -- flies under softmax ------
    #pragma unroll
    for (int t = 0; t < 5; ++t)
        vbuf1[t] = *(const f32x4*)(vcol + (size_t)(5 + t) * HID);
    const f32x4 vN4 = *(const f32x4*)(vcol + (size_t)NKQ * HID);

    __syncthreads();

    // ---------------- phase 2: softmax; normalized P stays in sc -----------
    {
        const int row = tid >> 5, t32 = tid & 31;
        const int gi  = i0 + row;
        float mx = -1e30f;
        for (int j = t32; j < SEQ; j += 32) {
            float s = sc[row][j] * INV_TEMP;
            sc[row][j] = s;
            mx = fmaxf(mx, s);
        }
        #pragma unroll
        for (int off = 1; off < 32; off <<= 1) mx = fmaxf(mx, __shfl_xor(mx, off));
        float sum = 0.f;
        for (int j = t32; j < SEQ; j += 32) {
            float e = __expf(sc[row][j] - mx);
            sc[row][j] = e;
            sum += e;
        }
        #pragma unroll
        for (int off = 1; off < 32; off <<= 1) sum += __shfl_xor(sum, off);
        const float inv = 1.f / sum;
        float* arow = attn + ((size_t)b * SEQ + gi) * SEQ;
        for (int j = t32; j < SEQ; j += 32) {
            float a = sc[row][j] * inv;
            sc[row][j] = a;                 // PV reads P from LDS
            if (gi < SEQ) arow[j] = a;      // tuple output
        }
    }
    __syncthreads();

    // ---------------- phase 3: fp32 streaming PV, windowed prefetch --------
    {
        int cir[4];
        #pragma unroll
        for (int rr = 0; rr < 4; ++rr)
            cir[rr] = (i0 + rg * 4 + rr) / KCLS;   // class of row (>=10: none)

        f32x4 accT[4] = {}, accU[4] = {};
        #pragma unroll
        for (int cls = 0; cls < 10; ++cls) {
            f32x4 seg[4] = {};
            // pr slot map: (v0,v1) =
            //  pr0:(b0[0],b0[1]) pr1:(b0[2],b0[3]) pr2:(b0[4],b1[0])
            //  pr3:(b1[1],b1[2]) pr4:(b1[3],b1[4])  -- all static
            #pragma unroll
            for (int pr = 0; pr < 5; ++pr) {
                const int j = cls * KCLS + 2 * pr;     // even -> b64-aligned
                const int s0 = 2 * pr, s1 = 2 * pr + 1;
                const f32x4 va = (s0 < 5) ? vbuf0[s0 < 5 ? s0 : 0] : vbuf1[s0 - 5];
                const f32x4 vc = (s1 < 5) ? vbuf0[s1 < 5 ? s1 : 0] : vbuf1[s1 - 5];
                #pragma unroll
                for (int rr = 0; rr < 4; ++rr) {
                    const float2 p2 = *(const float2*)&sc[rg * 4 + rr][j];
                    seg[rr] += vspl(p2.x) * va + vspl(p2.y) * vc;
                }
                if (pr == 2 && cls < 9) {
                    // window 2cls fully consumed -> refill with window 2cls+2
                    #pragma unroll
                    for (int t = 0; t < 5; ++t)
                        vbuf0[t] = *(const f32x4*)(vcol + (size_t)(cls * KCLS + 10 + t) * HID);
                }
            }
            if (cls < 9) {
                // window 2cls+1 consumed -> refill with window 2cls+3
                #pragma unroll
                for (int t = 0; t < 5; ++t)
                    vbuf1[t] = *(const f32x4*)(vcol + (size_t)(cls * KCLS + 15 + t) * HID);
            }
            #pragma unroll
            for (int rr = 0; rr < 4; ++rr) {
                accT[rr] += seg[rr];
                if (cls == cir[rr]) accU[rr] = seg[rr];
            }
        }
        // j = 100 (query row) contributes to T only
        #pragma unroll
        for (int rr = 0; rr < 4; ++rr)
            accT[rr] += vspl(sc[rg * 4 + rr][NKQ]) * vN4;

        // epilogue (all fp32, float4-wide)
        const f32x4 w0 = *(const f32x4*)(aw + 0 * HID + h4);
        const f32x4 w1 = *(const f32x4*)(aw + 1 * HID + h4);
        const f32x4 w2 = *(const f32x4*)(aw + 2 * HID + h4);
        const f32x4 w3 = *(const f32x4*)(aw + 3 * HID + h4);
        const f32x4 w4 = *(const f32x4*)(aw + 4 * HID + h4);
        const f32x4 w5 = *(const f32x4*)(aw + 5 * HID + h4);
        #pragma unroll
        for (int rr = 0; rr < 4; ++rr) {
            const int il = rg * 4 + rr;
            const int i  = i0 + il;
            if (i >= SEQ) continue;
            const float aiN = sc[il][NKQ];
            f32x4 o;
            if (i < NKQ) {
                const float aii = sc[il][i];
                const f32x4 vi  = *(const f32x4*)(vcol + (size_t)i * HID);
                o = w2 * accT[rr] + (w1 - w2) * accU[rr]
                  + (w0 - w1) * vspl(aii) * vi
                  + (w3 - w2) * vspl(aiN) * vN4;
            } else {
                o = w4 * accT[rr] + (w5 - w4) * vspl(aiN) * vN4;
            }
            *(f32x4*)(out + ((size_t)b * SEQ + i) * HID + h4) = o;
        }
    }
}

extern "C" void kernel_launch(void* const* d_in, const int* in_sizes, int n_in,
                              void* d_out, int out_size, void* d_ws, size_t ws_size,
                              hipStream_t stream) {
    const float* q  = (const float*)d_in[0];
    const float* k  = (const float*)d_in[1];
    const float* v  = (const float*)d_in[2];
    const float* aw = (const float*)d_in[3];
    float* out  = (float*)d_out;
    float* attn = out + (size_t)BATCH * SEQ * HID;   // tuple output: [out | attn]
    (void)d_ws; (void)ws_size;

    fused_attn<<<dim3(448), dim3(512), 0, stream>>>(q, k, v, aw, out, attn);
}

// Round 11
// 110.625 us; speedup vs baseline: 5.2082x; 5.2082x over previous
//
#include <hip/hip_runtime.h>
#include <math.h>
#include <stdint.h>

#define BATCH 64
#define SEQ   101
#define HID   512
#define NKQ   100      // N*K
#define KCLS  10
#define INV_TEMP 0.04419417382415922f   // 1/sqrt(512)

typedef short bf16x8 __attribute__((ext_vector_type(8)));
typedef float f32x4  __attribute__((ext_vector_type(4)));
typedef uint32_t u32x4 __attribute__((ext_vector_type(4)));

// HW packed f32->bf16 RNE: dst.lo = bf16(a), dst.hi = bf16(b)
__device__ inline uint32_t cvt2(float a, float b) {
    uint32_t r;
    asm("v_cvt_pk_bf16_f32 %0, %1, %2" : "=v"(r) : "v"(a), "v"(b));
    return r;
}
// truncation split: x == hi + lo to ~2^-17 rel (q & P planes)
__device__ inline void split_bf16(float x, short& hi, short& lo) {
    uint32_t u = __builtin_bit_cast(uint32_t, x);
    hi = (short)(u >> 16);
    float hf = __builtin_bit_cast(float, u & 0xFFFF0000u);
    float l  = x - hf;
    lo = (short)(__builtin_bit_cast(uint32_t, l) >> 16);
}

// ---------------------------------------------------------------------------
// BEST-KNOWN kernel (round 3, measured 110.95 us total) with ONE change:
// __launch_bounds__(512, 4) -> (512, 2).
// Rationale: (512,4) capped the allocator at 64 VGPR (proven r6->r7: same
// source, (512,2) went 64->84 VGPR and eliminated 18 MB of scratch traffic).
// Grid is 448/256CU = 1.75 blocks/CU -- occupancy above 2 blocks/CU is
// unusable, so the register headroom is free. This kernel's fully-unrolled
// phase 3 (xv[2][8] + Ah/Al[4] + T/U + addrs) sits exactly at the 64-VGPR
// boundary; lifting the cap lets it live in registers with room to schedule.
//   phase 1: QK^T -- q staged hi/lo in LDS once (1 barrier), k fragments read
//            DIRECTLY from global (row-major matches MFMA B layout) + cvt_pk.
//   phase 2: softmax, P normalized in LDS sc.
//   phase 3: PV -- ZERO barriers, ZERO LDS. B-fragment element e for lane
//            (m,g) is V[ks*32+g*8+e][hc*128+hl]; 16 lanes of a g-group read
//            64B coalesced segments; V is L2-resident across same-b blocks
//            (same XCD: ids differ by 64 = 0 mod 8). hi/lo split in-register.
// LDS: q hi/lo 32.5 KB + sc 8.4 KB = 40.9 KB. grid 448: b=id&63, i-tile=id>>6.
// ---------------------------------------------------------------------------
#define QST 520    // qhi/qlo row stride (shorts): 512 + 8 pad

#define OFF_QLO 16640          // 16*520*2
#define POOLSZ  33280          // 2*16640

__global__ __launch_bounds__(512, 2)
void fused_attn(const float* __restrict__ q, const float* __restrict__ k,
                const float* __restrict__ v, const float* __restrict__ aw,
                float* __restrict__ out, float* __restrict__ attn) {
    __shared__ __align__(16) char pool[POOLSZ];
    __shared__ __align__(16) float sc[16][132];
    short (*qhi)[QST] = (short(*)[QST])(pool);
    short (*qlo)[QST] = (short(*)[QST])(pool + OFF_QLO);

    const int b   = blockIdx.x & 63;
    const int i0  = (blockIdx.x >> 6) * 16;
    const int tid = threadIdx.x;
    const int wv  = tid >> 6, lane = tid & 63;
    const int m   = lane & 15;
    const int g   = lane >> 4;
    const int kq  = g * 8;
    const int rq  = g * 4;
    const int j0w = wv * 16;

    const float* qb = q + (size_t)b * SEQ * HID;
    const float* kb = k + (size_t)b * SEQ * HID;
    const float* vb = v + (size_t)b * SEQ * HID;

    // ---------------- stage q hi/lo (once) ---------------------------------
    #pragma unroll
    for (int s = 0; s < 4; ++s) {
        const int f = tid + s * 512;
        const int r = f >> 7, c = (f & 127) << 2;
        const int gi = i0 + r;
        f32x4 x = {};
        if (gi < SEQ) x = *(const f32x4*)(qb + (size_t)gi * HID + c);
        short4 hv, lv;
        split_bf16(x[0], hv.x, lv.x);
        split_bf16(x[1], hv.y, lv.y);
        split_bf16(x[2], hv.z, lv.z);
        split_bf16(x[3], hv.w, lv.w);
        *(short4*)&qhi[r][c] = hv;
        *(short4*)&qlo[r][c] = lv;
    }
    __syncthreads();

    // ---------------- phase 1: QK^T, k direct from global, no barriers -----
    f32x4 acc = {};
    {
        const int jg = j0w + m;
        const int jr = (jg > NKQ) ? NKQ : jg;   // clamp; junk cols zeroed later
        const float* kr = kb + (size_t)jr * HID + kq;
        f32x4 k0 = *(const f32x4*)(kr);
        f32x4 k1 = *(const f32x4*)(kr + 4);
        #pragma unroll
        for (int ks = 0; ks < 16; ++ks) {
            f32x4 n0 = {}, n1 = {};
            if (ks < 15) {
                n0 = *(const f32x4*)(kr + (ks + 1) * 32);
                n1 = *(const f32x4*)(kr + (ks + 1) * 32 + 4);
            }
            u32x4 kp;
            kp[0] = cvt2(k0[0], k0[1]); kp[1] = cvt2(k0[2], k0[3]);
            kp[2] = cvt2(k1[0], k1[1]); kp[3] = cvt2(k1[2], k1[3]);
            const bf16x8 kH = __builtin_bit_cast(bf16x8, kp);
            const bf16x8 qH = *(const bf16x8*)&qhi[m][ks * 32 + kq];
            const bf16x8 qL = *(const bf16x8*)&qlo[m][ks * 32 + kq];
            acc = __builtin_amdgcn_mfma_f32_16x16x32_bf16(qH, kH, acc, 0, 0, 0);
            acc = __builtin_amdgcn_mfma_f32_16x16x32_bf16(qL, kH, acc, 0, 0, 0);
            k0 = n0; k1 = n1;
        }
    }
    #pragma unroll
    for (int r = 0; r < 4; ++r)
        sc[rq + r][j0w + m] = acc[r];
    __syncthreads();

    // ---------------- phase 2: softmax; normalized P stays in sc -----------
    {
        const int row = tid >> 5, t32 = tid & 31;
        const int gi  = i0 + row;
        float mx = -1e30f;
        for (int j = t32; j < SEQ; j += 32) {
            float s = sc[row][j] * INV_TEMP;
            sc[row][j] = s;
            mx = fmaxf(mx, s);
        }
        #pragma unroll
        for (int off = 1; off < 32; off <<= 1) mx = fmaxf(mx, __shfl_xor(mx, off));
        float sum = 0.f;
        for (int j = t32; j < SEQ; j += 32) {
            float e = __expf(sc[row][j] - mx);
            sc[row][j] = e;
            sum += e;
        }
        #pragma unroll
        for (int off = 1; off < 32; off <<= 1) sum += __shfl_xor(sum, off);
        const float inv = 1.f / sum;
        float* arow = attn + ((size_t)b * SEQ + gi) * SEQ;
        for (int j = t32; j < SEQ; j += 32) {
            float a = sc[row][j] * inv;
            sc[row][j] = a;                 // PV reads P from LDS
            if (gi < SEQ) arow[j] = a;      // tuple output
        }
        for (int j = SEQ + t32; j < 128; j += 32) sc[row][j] = 0.f;  // pad cols
    }
    __syncthreads();

    // ---------------- A fragments + class mask (hoisted) --------------------
    int ai = i0 + m; if (ai > NKQ) ai = NKQ;
    const int ci = ai / KCLS;
    uint32_t mbits = 0;
    #pragma unroll
    for (int ks = 0; ks < 4; ++ks)
        #pragma unroll
        for (int e = 0; e < 8; ++e)
            if (((ks * 32 + kq + e) / KCLS) == ci) mbits |= (1u << (ks * 8 + e));
    bf16x8 Ah[4], Al[4];
    #pragma unroll
    for (int ks = 0; ks < 4; ++ks) {
        const f32x4 u0 = *(const f32x4*)&sc[m][ks * 32 + kq];
        const f32x4 u1 = *(const f32x4*)&sc[m][ks * 32 + kq + 4];
        const float x[8] = {u0[0], u0[1], u0[2], u0[3], u1[0], u1[1], u1[2], u1[3]};
        #pragma unroll
        for (int e = 0; e < 8; ++e) {
            short h, l; split_bf16(x[e], h, l);
            Ah[ks][e] = h; Al[ks][e] = l;
        }
    }

    // ---------------- phase 3: PV direct-from-global, no barriers -----------
    const int hl = j0w + m;                    // local h (0..127) this lane owns
    for (int hc = 0; hc < 4; ++hc) {
        const int h = (hc << 7) + hl;
        const float* vh = vb + h;
        f32x4 T = {}, U = {};
        #pragma unroll
        for (int ks = 0; ks < 4; ++ks) {
            float xv[8];
            #pragma unroll
            for (int e = 0; e < 8; ++e) {
                const int j  = ks * 32 + kq + e;
                const int jr = (j > NKQ) ? NKQ : j;   // P=0 for j>100 nullifies
                xv[e] = vh[(size_t)jr * HID];
            }
            u32x4 ph, pl;
            #pragma unroll
            for (int p = 0; p < 4; ++p) {
                const uint32_t h01 = cvt2(xv[2 * p], xv[2 * p + 1]);
                const float r0 = xv[2 * p]     - __builtin_bit_cast(float, h01 << 16);
                const float r1 = xv[2 * p + 1] - __builtin_bit_cast(float, h01 & 0xFFFF0000u);
                ph[p] = h01;
                pl[p] = cvt2(r0, r1);
            }
            const bf16x8 Bh = __builtin_bit_cast(bf16x8, ph);
            const bf16x8 Bl = __builtin_bit_cast(bf16x8, pl);
            bf16x8 Mh;
            #pragma unroll
            for (int e = 0; e < 8; ++e)
                Mh[e] = (mbits & (1u << (ks * 8 + e))) ? Ah[ks][e] : (short)0;
            T = __builtin_amdgcn_mfma_f32_16x16x32_bf16(Ah[ks], Bh, T, 0, 0, 0);
            T = __builtin_amdgcn_mfma_f32_16x16x32_bf16(Ah[ks], Bl, T, 0, 0, 0);
            T = __builtin_amdgcn_mfma_f32_16x16x32_bf16(Al[ks], Bh, T, 0, 0, 0);
            U = __builtin_amdgcn_mfma_f32_16x16x32_bf16(Mh,     Bh, U, 0, 0, 0);
        }
        // epilogue for this h-chunk
        const float w0 = aw[0 * HID + h], w1 = aw[1 * HID + h], w2 = aw[2 * HID + h];
        const float w3 = aw[3 * HID + h], w4 = aw[4 * HID + h], w5 = aw[5 * HID + h];
        const float vN = vb[(size_t)NKQ * HID + h];
        #pragma unroll
        for (int r = 0; r < 4; ++r) {
            const int i = i0 + rq + r;
            if (i >= SEQ) continue;
            const int il = rq + r;
            const float t = T[r], u = U[r];
            const float aiN = sc[il][NKQ];
            float o;
            if (i < NKQ) {
                const float aii = sc[il][i];
                const float vi  = vb[(size_t)i * HID + h];
                o = w2 * t + (w1 - w2) * u + (w0 - w1) * aii * vi + (w3 - w2) * aiN * vN;
            } else {
                o = w4 * t + (w5 - w4) * aiN * vN;
            }
            out[((size_t)b * SEQ + i) * HID + h] = o;
        }
    }
}

extern "C" void kernel_launch(void* const* d_in, const int* in_sizes, int n_in,
                              void* d_out, int out_size, void* d_ws, size_t ws_size,
                              hipStream_t stream) {
    const float* q  = (const float*)d_in[0];
    const float* k  = (const float*)d_in[1];
    const float* v  = (const float*)d_in[2];
    const float* aw = (const float*)d_in[3];
    float* out  = (float*)d_out;
    float* attn = out + (size_t)BATCH * SEQ * HID;   // tuple output: [out | attn]
    (void)d_ws; (void)ws_size;

    fused_attn<<<dim3(448), dim3(512), 0, stream>>>(q, k, v, aw, out, attn);
}